// Round 1
// baseline (228.708 us; speedup 1.0000x reference)
//
#include <hip/hip_runtime.h>
#include <math.h>

// B=4, T=512, IDIM=128, HDIM=1024, CDIM=256
#define NROWS 2048
#define NBLK  2048            // one row per block, 2 waves per block
#define NITER 4
#define IGNORE_OUT 10000.0f
#define LOG2E 1.44269504088896340736f

__device__ __forceinline__ float readlanef(float v, int lane){
  return __int_as_float(__builtin_amdgcn_readlane(__float_as_int(v), lane));
}

// ---- DPP wave primitives (gfx9 ladder: row_shr 1/2/4/8, bcast15->rows1,3, bcast31->rows2,3) ----
__device__ __forceinline__ float waveScanInc(float v){
  v += __int_as_float(__builtin_amdgcn_update_dpp(0, __float_as_int(v), 0x111, 0xF, 0xF, true));
  v += __int_as_float(__builtin_amdgcn_update_dpp(0, __float_as_int(v), 0x112, 0xF, 0xF, true));
  v += __int_as_float(__builtin_amdgcn_update_dpp(0, __float_as_int(v), 0x114, 0xF, 0xF, true));
  v += __int_as_float(__builtin_amdgcn_update_dpp(0, __float_as_int(v), 0x118, 0xF, 0xF, true));
  v += __int_as_float(__builtin_amdgcn_update_dpp(0, __float_as_int(v), 0x142, 0xA, 0xF, true));
  v += __int_as_float(__builtin_amdgcn_update_dpp(0, __float_as_int(v), 0x143, 0xC, 0xF, true));
  return v;                                // lane l = sum of lanes 0..l
}
__device__ __forceinline__ float waveSum(float v){
  return readlanef(waveScanInc(v), 63);
}
__device__ __forceinline__ void waveArgmax(float &v, int &i){
#define AMSTEP(ctrl, rm) { \
    float ov = __int_as_float(__builtin_amdgcn_update_dpp(__float_as_int(v), __float_as_int(v), ctrl, rm, 0xF, false)); \
    int   oi = __builtin_amdgcn_update_dpp(i, i, ctrl, rm, 0xF, false); \
    bool take = (ov > v) || (ov == v && oi < i); \
    v = take ? ov : v; i = take ? oi : i; }
  AMSTEP(0x111, 0xF) AMSTEP(0x112, 0xF) AMSTEP(0x114, 0xF)
  AMSTEP(0x118, 0xF) AMSTEP(0x142, 0xA) AMSTEP(0x143, 0xC)
#undef AMSTEP
  v = readlanef(v, 63);
  i = __builtin_amdgcn_readlane(i, 63);
}
// paired gather: a = vec[idx], b = vec[idx+64] (0 outside [0,128)); 2 bpermutes total
__device__ __forceinline__ void gatherPair(float v0, float v1, int idx, float &a, float &b){
  int c = idx & 63;
  float g0 = __shfl(v0, c, 64);
  float g1 = __shfl(v1, c, 64);
  a = ((unsigned)idx < 128u) ? ((idx & 64) ? g1 : g0) : 0.f;
  int idx2 = idx + 64;
  b = ((unsigned)idx2 < 128u) ? ((idx2 & 64) ? g1 : g0) : 0.f;
}

// ---------- prep kernel: M4[i] = w2[:, i*256:(i+1)*256] @ w1[i*256:(i+1)*256, :] ----------
__global__ __launch_bounds__(128)
void prepK(const float* __restrict__ w1, const float* __restrict__ b1,
           const float* __restrict__ w2, const float* __restrict__ b2,
           float* __restrict__ M4, float* __restrict__ biasT, int* __restrict__ ticket){
  const int blk = blockIdx.x;
  const int u = threadIdx.x;
  if (blk < 512){
    int i = blk >> 7, o = blk & 127;
    const float* w1p = w1 + (i * 256) * 128 + u;   // coalesced over d=u
    const float* w2p = w2 + o * 1024 + i * 256;    // thread-uniform (scalar loads)
    float a0 = 0.f, a1 = 0.f, a2 = 0.f, a3 = 0.f;  // 4 chains (was 1x 256-deep)
    #pragma unroll 16
    for (int c = 0; c < 256; c += 4){
      a0 = fmaf(w1p[(c + 0) * 128], w2p[c + 0], a0);
      a1 = fmaf(w1p[(c + 1) * 128], w2p[c + 1], a1);
      a2 = fmaf(w1p[(c + 2) * 128], w2p[c + 2], a2);
      a3 = fmaf(w1p[(c + 3) * 128], w2p[c + 3], a3);
    }
    M4[i * 16384 + (u >> 2) * 512 + o * 4 + (u & 3)] = (a0 + a1) + (a2 + a3);
  } else if (blk < 516){
    int i = blk - 512;
    const float* w2p = w2 + u * 1024 + i * 256;
    const float* b1p = b1 + i * 256;
    float a0 = b2[u], a1 = 0.f, a2 = 0.f, a3 = 0.f;
    #pragma unroll 8
    for (int c = 0; c < 256; c += 4){
      a0 = fmaf(b1p[c + 0], w2p[c + 0], a0);
      a1 = fmaf(b1p[c + 1], w2p[c + 1], a1);
      a2 = fmaf(b1p[c + 2], w2p[c + 2], a2);
      a3 = fmaf(b1p[c + 3], w2p[c + 3], a3);
    }
    biasT[i * 128 + u] = (a0 + a1) + (a2 + a3);
  } else {
    if (u == 0) *ticket = 0;
  }
}

// ---------- main kernel ----------
// wave w handles shift-pair t = 64w + l (shifts t and t+128), full j range [0,128)
// window value for (t, j) = ydlin[(255 - t) + j], where ydlin[128+k] = ydlin[256+k] = y_res[k].
// ydc[r][k] = ydlin[k + r] (4 shift-aligned copies, stride 392 to spread banks) so each lane
// can read its window with aligned ds_read_b128: r = A&3, base = A&~3, A = 255-u.
__global__ __launch_bounds__(128, 4)
void mainK(const float* __restrict__ x, const float* __restrict__ y,
           const float* __restrict__ M4, const float* __restrict__ biasT,
           unsigned long long* __restrict__ partials, int* __restrict__ ticket,
           float* __restrict__ out){
  __shared__ float ydc[4][392];   // shift-aligned y window copies (shared by both waves)
  __shared__ float xbuf[2][128];  // per-wave x_res copy (broadcast source)
  __shared__ float wbuf[2][128];  // per-wave x_attn copy (MLP broadcast source)
  __shared__ float sVal[2];
  __shared__ int   sIdx[2];
  __shared__ float sL[2], sC[2];
  __shared__ int   sOld;

  const int u = threadIdx.x;               // 0..127 ; u = 64w + l = owned element / output
  const int l = u & 63;
  const int w = u >> 6;
  const long base = (long)blockIdx.x * 128;

  float xlo = x[base + l], xhi = x[base + 64 + l];   // both waves hold full x (elements l, 64+l)
  float ylo = y[base + l], yhi = y[base + 64 + l];
  const float yOwn0 = w ? yhi : ylo;
  const bool mOwn = (yOwn0 == IGNORE_OUT);
  float cnt = mOwn ? 0.f : 1.f;
  float lossAcc = 0.f;

  // initial shared state: y window copies (cross-wave, needs barrier) + per-wave x copy
  #pragma unroll
  for (int r = 0; r < 4; ++r){ ydc[r][128 + u - r] = yOwn0; ydc[r][256 + u - r] = yOwn0; }
  xbuf[w][l] = xlo; xbuf[w][64 + l] = xhi;
  __syncthreads();

  const int A = 255 - u;
  const float4* wrow = (const float4*)&ydc[A & 3][A & ~3];  // 1568B rows -> 16B aligned
  const float4* xrow = (const float4*)&xbuf[w][0];
  const float4* wbv  = (const float4*)&wbuf[w][0];

  for (int i = 0; i < NITER; ++i){
    const float4* Mp = (const float4*)(M4 + (size_t)i * 16384);
    // ---- prefetch MLP groups 0,1 + bias: latency hidden under scans + corr ----
    float4 mb[4][4];
    #pragma unroll
    for (int q = 0; q < 4; ++q) mb[0][q] = Mp[q * 128 + u];
    #pragma unroll
    for (int q = 0; q < 4; ++q) mb[1][q] = Mp[(4 + q) * 128 + u];
    float bias_i = biasT[i * 128 + u];

    // ---- window-norm prefix at t = 64w+l (DPP scan + DPP sums; zero DS) ----
    float own2 = w ? xhi * xhi : xlo * xlo;
    float oth2 = w ? xlo * xlo : xhi * xhi;
    float v = waveScanInc(own2);
    float osum  = waveSum(oth2);
    float total = readlanef(v, 63) + osum;
    float pref_t = w ? (v + osum) : v;     // inclusive prefix of x^2 at index t
    float ny2 = waveSum(ylo * ylo + yhi * yhi);

    // ---- corr: 32 b128 window reads + 32 uniform b128 x broadcasts; mask-fma prefix ----
    // Sh0 = sum_{j<64} W[j]x[j], Sh1 = sum_{j>=64}; P = masked prefix over own half (j_local<=l).
    float s0=0.f,s1=0.f,s2=0.f,s3=0.f, t0=0.f,t1=0.f,t2=0.f,t3=0.f, p0=0.f,p1=0.f,p2=0.f,p3=0.f;
    if (w == 0){
      #pragma unroll
      for (int m = 0; m < 16; ++m){
        float4 wv = wrow[m], xv = xrow[m];
        s0 = fmaf(wv.x, xv.x, s0); s1 = fmaf(wv.y, xv.y, s1);
        s2 = fmaf(wv.z, xv.z, s2); s3 = fmaf(wv.w, xv.w, s3);
        const int jb = 4 * m;
        p0 = fmaf(wv.x, (l >= jb    ) ? xv.x : 0.f, p0);
        p1 = fmaf(wv.y, (l >= jb + 1) ? xv.y : 0.f, p1);
        p2 = fmaf(wv.z, (l >= jb + 2) ? xv.z : 0.f, p2);
        p3 = fmaf(wv.w, (l >= jb + 3) ? xv.w : 0.f, p3);
      }
      #pragma unroll
      for (int m = 16; m < 32; ++m){
        float4 wv = wrow[m], xv = xrow[m];
        t0 = fmaf(wv.x, xv.x, t0); t1 = fmaf(wv.y, xv.y, t1);
        t2 = fmaf(wv.z, xv.z, t2); t3 = fmaf(wv.w, xv.w, t3);
      }
    } else {
      #pragma unroll
      for (int m = 0; m < 16; ++m){
        float4 wv = wrow[m], xv = xrow[m];
        s0 = fmaf(wv.x, xv.x, s0); s1 = fmaf(wv.y, xv.y, s1);
        s2 = fmaf(wv.z, xv.z, s2); s3 = fmaf(wv.w, xv.w, s3);
      }
      #pragma unroll
      for (int m = 16; m < 32; ++m){
        float4 wv = wrow[m], xv = xrow[m];
        t0 = fmaf(wv.x, xv.x, t0); t1 = fmaf(wv.y, xv.y, t1);
        t2 = fmaf(wv.z, xv.z, t2); t3 = fmaf(wv.w, xv.w, t3);
        const int jb = 4 * m - 64;
        p0 = fmaf(wv.x, (l >= jb    ) ? xv.x : 0.f, p0);
        p1 = fmaf(wv.y, (l >= jb + 1) ? xv.y : 0.f, p1);
        p2 = fmaf(wv.z, (l >= jb + 2) ? xv.z : 0.f, p2);
        p3 = fmaf(wv.w, (l >= jb + 3) ? xv.w : 0.f, p3);
      }
    }
    float Sh0 = (s0 + s1) + (s2 + s3);
    float Sh1 = (t0 + t1) + (t2 + t3);
    float P   = (p0 + p1) + (p2 + p3);
    float nt = Sh0 + Sh1;
    float n1 = w ? (Sh0 + P) : P;

    // ---- cosine sims via v_rsq; DPP argmax; cross-wave combine ----
    {
      bool yz = (ny2 == 0.f);
      float rNY = __builtin_amdgcn_rsqf(ny2);       // 1/||y||
      float nx2b = fmaxf(total - pref_t, 0.f);
      float s1v = (yz || pref_t == 0.f) ? 0.f : n1 * __builtin_amdgcn_rsqf(pref_t) * rNY;
      float s2v = (yz || nx2b  == 0.f) ? 0.f : (nt - n1) * __builtin_amdgcn_rsqf(nx2b) * rNY;
      if (u == 127) s2v = -INFINITY;       // shift 255 doesn't exist
      float bv = s1v; int bi = u;
      if (s2v > bv){ bv = s2v; bi = u + 128; }
      waveArgmax(bv, bi);
      if (l == 0){ sVal[w] = bv; sIdx[w] = bi; }
    }
    __syncthreads();                       // B1

    // ---- prefetch MLP groups 2,3: latency hidden under softmax/gathers ----
    #pragma unroll
    for (int q = 0; q < 4; ++q) mb[2][q] = Mp[(8 + q) * 128 + u];
    #pragma unroll
    for (int q = 0; q < 4; ++q) mb[3][q] = Mp[(12 + q) * 128 + u];

    int sstar;
    {
      float v0 = sVal[0], v1 = sVal[1];
      int   i0 = sIdx[0], i1 = sIdx[1];
      sstar = (v1 > v0 || (v1 == v0 && i1 < i0)) ? i1 : i0;
    }

    // ---- x_aug + detached softmax (hw exp2/rcp; paired gathers) ----
    float xa, xb;
    gatherPair(xlo, xhi, sstar + l - 127, xa, xb);
    float ea = __builtin_amdgcn_exp2f(xa * ylo * LOG2E);
    float eb = __builtin_amdgcn_exp2f(xb * yhi * LOG2E);
    float rse = __builtin_amdgcn_rcpf(waveSum(ea + eb));
    float wlo = xa * (ea * rse), whi = xb * (eb * rse);   // xatt

    // ---- x_res update (reverse shift, paired gather) ----
    {
      float ga, gb;
      gatherPair(wlo, whi, l + 127 - sstar, ga, gb);
      xlo -= ga; xhi -= gb;
    }
    // publish per-wave broadcast copies (same-wave RAW, no barrier needed)
    xbuf[w][l] = xlo; xbuf[w][64 + l] = xhi;   // for next iter's corr
    wbuf[w][l] = wlo; wbuf[w][64 + l] = whi;   // for MLP broadcasts below

    // ---- MLP: thread u -> output o = u; pipelined b128 loads + LDS uniform broadcasts ----
    float ye;
    {
      float a0 = 0.f, a1 = 0.f, a2 = 0.f, a3 = 0.f;
      #pragma unroll
      for (int g = 0; g < 8; ++g){
        float4 m0 = mb[g & 3][0], m1 = mb[g & 3][1], m2 = mb[g & 3][2], m3 = mb[g & 3][3];
        if (g < 4){                        // prefetch group g+4 into the slot just freed
          #pragma unroll
          for (int q = 0; q < 4; ++q) mb[g & 3][q] = Mp[((g + 4) * 4 + q) * 128 + u];
        }
        float4 b0 = wbv[4 * g + 0], b1 = wbv[4 * g + 1], b2 = wbv[4 * g + 2], b3 = wbv[4 * g + 3];
        a0 = fmaf(m0.x, b0.x, a0); a0 = fmaf(m0.y, b0.y, a0); a0 = fmaf(m0.z, b0.z, a0); a0 = fmaf(m0.w, b0.w, a0);
        a1 = fmaf(m1.x, b1.x, a1); a1 = fmaf(m1.y, b1.y, a1); a1 = fmaf(m1.z, b1.z, a1); a1 = fmaf(m1.w, b1.w, a1);
        a2 = fmaf(m2.x, b2.x, a2); a2 = fmaf(m2.y, b2.y, a2); a2 = fmaf(m2.z, b2.z, a2); a2 = fmaf(m2.w, b2.w, a2);
        a3 = fmaf(m3.x, b3.x, a3); a3 = fmaf(m3.y, b3.y, a3); a3 = fmaf(m3.z, b3.z, a3); a3 = fmaf(m3.w, b3.w, a3);
      }
      ye = ((a0 + a1) + (a2 + a3)) + bias_i;
    }

    // ---- loss on owned element + publish new y_res (safe: both waves are past B1) ----
    {
      float yOwn = w ? yhi : ylo;
      float df = ye - yOwn;
      if (!mOwn) lossAcc = fmaf(df, df, lossAcc);
      float yNew = yOwn - ye;
      #pragma unroll
      for (int r = 0; r < 4; ++r){ ydc[r][128 + u - r] = yNew; ydc[r][256 + u - r] = yNew; }
    }
    __syncthreads();                       // B2
    ylo = ydc[0][128 + l];                 // refresh register copies
    yhi = ydc[0][192 + l];
  }

  // ---- block loss/cnt, partial store + ticket; last block finalizes ----
  lossAcc = waveSum(lossAcc);
  cnt     = waveSum(cnt);
  if (l == 0){ sL[w] = lossAcc; sC[w] = cnt; }
  __syncthreads();
  if (u == 0){
    union { float2 f; unsigned long long v; } pk;
    pk.f.x = sL[0] + sL[1];
    pk.f.y = sC[0] + sC[1];
    __hip_atomic_store(&partials[blockIdx.x], pk.v, __ATOMIC_RELEASE, __HIP_MEMORY_SCOPE_AGENT);
    sOld = __hip_atomic_fetch_add(ticket, 1, __ATOMIC_ACQ_REL, __HIP_MEMORY_SCOPE_AGENT);
  }
  __syncthreads();
  if (sOld == NBLK - 1){
    float ls = 0.f, cs = 0.f;
    for (int g = u; g < NBLK; g += 128){
      union { float2 f; unsigned long long v; } pk;
      pk.v = __hip_atomic_load(&partials[g], __ATOMIC_ACQUIRE, __HIP_MEMORY_SCOPE_AGENT);
      ls += pk.f.x; cs += pk.f.y;
    }
    ls = waveSum(ls); cs = waveSum(cs);
    if (l == 0){ sL[w] = ls; sC[w] = cs; }
    __syncthreads();
    if (u == 0) out[0] = (sL[0] + sL[1]) / ((float)NITER * (sC[0] + sC[1]));
  }
}

extern "C" void kernel_launch(void* const* d_in, const int* in_sizes, int n_in,
                              void* d_out, int out_size, void* d_ws, size_t ws_size,
                              hipStream_t stream){
  const float* x  = (const float*)d_in[0];
  const float* y  = (const float*)d_in[1];
  const float* w1 = (const float*)d_in[2];
  const float* b1 = (const float*)d_in[3];
  const float* w2 = (const float*)d_in[4];
  const float* b2 = (const float*)d_in[5];
  float* out = (float*)d_out;

  // ws: [0,4) ticket ; [256, 256+256K) M4 ; +2K biasT ; +16K partials
  int*   ticket = (int*)d_ws;
  float* M4     = (float*)((char*)d_ws + 256);
  float* biasT  = (float*)((char*)d_ws + 256 + 4 * 128 * 128 * sizeof(float));
  unsigned long long* partials =
      (unsigned long long*)((char*)d_ws + 256 + 4 * 128 * 128 * sizeof(float) + 4 * 128 * sizeof(float));

  prepK<<<517, 128, 0, stream>>>(w1, b1, w2, b2, M4, biasT, ticket);
  mainK<<<NBLK, 128, 0, stream>>>(x, y, M4, biasT, partials, ticket, out);
}

// Round 2
// 176.837 us; speedup vs baseline: 1.2933x; 1.2933x over previous
//
#include <hip/hip_runtime.h>
#include <math.h>

// B=4, T=512, IDIM=128, HDIM=1024, CDIM=256
#define NBLK  2048            // one row per block, 2 waves per block
#define NITER 4
#define IGNORE_OUT 10000.0f
#define LOG2E 1.44269504088896340736f

__device__ __forceinline__ float readlanef(float v, int lane){
  return __int_as_float(__builtin_amdgcn_readlane(__float_as_int(v), lane));
}

// ---- DPP wave primitives (gfx9 ladder: row_shr 1/2/4/8, bcast15->rows1,3, bcast31->rows2,3) ----
__device__ __forceinline__ float waveScanInc(float v){
  v += __int_as_float(__builtin_amdgcn_update_dpp(0, __float_as_int(v), 0x111, 0xF, 0xF, true));
  v += __int_as_float(__builtin_amdgcn_update_dpp(0, __float_as_int(v), 0x112, 0xF, 0xF, true));
  v += __int_as_float(__builtin_amdgcn_update_dpp(0, __float_as_int(v), 0x114, 0xF, 0xF, true));
  v += __int_as_float(__builtin_amdgcn_update_dpp(0, __float_as_int(v), 0x118, 0xF, 0xF, true));
  v += __int_as_float(__builtin_amdgcn_update_dpp(0, __float_as_int(v), 0x142, 0xA, 0xF, true));
  v += __int_as_float(__builtin_amdgcn_update_dpp(0, __float_as_int(v), 0x143, 0xC, 0xF, true));
  return v;                                // lane l = sum of lanes 0..l
}
__device__ __forceinline__ float waveSum(float v){
  return readlanef(waveScanInc(v), 63);
}
__device__ __forceinline__ void waveArgmax(float &v, int &i){
#define AMSTEP(ctrl, rm) { \
    float ov = __int_as_float(__builtin_amdgcn_update_dpp(__float_as_int(v), __float_as_int(v), ctrl, rm, 0xF, false)); \
    int   oi = __builtin_amdgcn_update_dpp(i, i, ctrl, rm, 0xF, false); \
    bool take = (ov > v) || (ov == v && oi < i); \
    v = take ? ov : v; i = take ? oi : i; }
  AMSTEP(0x111, 0xF) AMSTEP(0x112, 0xF) AMSTEP(0x114, 0xF)
  AMSTEP(0x118, 0xF) AMSTEP(0x142, 0xA) AMSTEP(0x143, 0xC)
#undef AMSTEP
  v = readlanef(v, 63);
  i = __builtin_amdgcn_readlane(i, 63);
}
// paired gather: a = vec[idx], b = vec[idx+64] (0 outside [0,128)); 2 bpermutes total
__device__ __forceinline__ void gatherPair(float v0, float v1, int idx, float &a, float &b){
  int c = idx & 63;
  float g0 = __shfl(v0, c, 64);
  float g1 = __shfl(v1, c, 64);
  a = ((unsigned)idx < 128u) ? ((idx & 64) ? g1 : g0) : 0.f;
  int idx2 = idx + 64;
  b = ((unsigned)idx2 < 128u) ? ((idx2 & 64) ? g1 : g0) : 0.f;
}

// ---------- prep kernel: M4[i] = w2[:, i*256:(i+1)*256] @ w1[i*256:(i+1)*256, :] ----------
// 256 threads: h = tid>>7 splits the 256-deep K range in half (halves the exposed
// fma/load chain at this kernel's ~1 wave/SIMD occupancy), LDS combine.
__global__ __launch_bounds__(256)
void prepK(const float* __restrict__ w1, const float* __restrict__ b1,
           const float* __restrict__ w2, const float* __restrict__ b2,
           float* __restrict__ M4, float* __restrict__ biasT, int* __restrict__ ticket){
  const int blk = blockIdx.x;
  const int tid = threadIdx.x;
  const int u = tid & 127, h = tid >> 7;
  __shared__ float part[256];
  if (blk < 512){
    int i = blk >> 7, o = blk & 127;
    const float* w1p = w1 + (i * 256 + h * 128) * 128 + u;   // coalesced over d=u
    const float* w2p = w2 + o * 1024 + i * 256 + h * 128;    // thread-uniform
    float a0 = 0.f, a1 = 0.f, a2 = 0.f, a3 = 0.f;
    #pragma unroll 8
    for (int c = 0; c < 128; c += 4){
      a0 = fmaf(w1p[(c + 0) * 128], w2p[c + 0], a0);
      a1 = fmaf(w1p[(c + 1) * 128], w2p[c + 1], a1);
      a2 = fmaf(w1p[(c + 2) * 128], w2p[c + 2], a2);
      a3 = fmaf(w1p[(c + 3) * 128], w2p[c + 3], a3);
    }
    part[tid] = (a0 + a1) + (a2 + a3);
    __syncthreads();
    if (h == 0) M4[i * 16384 + (u >> 2) * 512 + o * 4 + (u & 3)] = part[u] + part[128 + u];
  } else if (blk < 516){
    int i = blk - 512;
    const float* w2p = w2 + u * 1024 + i * 256 + h * 128;
    const float* b1p = b1 + i * 256 + h * 128;
    float a0 = h ? 0.f : b2[u], a1 = 0.f, a2 = 0.f, a3 = 0.f;
    #pragma unroll 8
    for (int c = 0; c < 128; c += 4){
      a0 = fmaf(b1p[c + 0], w2p[c + 0], a0);
      a1 = fmaf(b1p[c + 1], w2p[c + 1], a1);
      a2 = fmaf(b1p[c + 2], w2p[c + 2], a2);
      a3 = fmaf(b1p[c + 3], w2p[c + 3], a3);
    }
    part[tid] = (a0 + a1) + (a2 + a3);
    __syncthreads();
    if (h == 0) biasT[i * 128 + u] = part[u] + part[128 + u];
  } else {
    if (tid == 0) *ticket = 0;
  }
}

// M-group load/consume macros — NAMED float4 scalars only (no arrays: spill-proof).
// Group gg covers M float4-rows 4gg..4gg+3 = k-values 16gg..16gg+15.
#define MLD(d0, d1, d2, d3, gg) \
  d0 = Mp[((gg) * 4 + 0) * 128 + u]; d1 = Mp[((gg) * 4 + 1) * 128 + u]; \
  d2 = Mp[((gg) * 4 + 2) * 128 + u]; d3 = Mp[((gg) * 4 + 3) * 128 + u];
#define MFM(m0, m1, m2, m3, src, kb) \
  a0 = fmaf((m0).x, readlanef(src, (kb) + 0), a0);  a0 = fmaf((m0).y, readlanef(src, (kb) + 1), a0); \
  a0 = fmaf((m0).z, readlanef(src, (kb) + 2), a0);  a0 = fmaf((m0).w, readlanef(src, (kb) + 3), a0); \
  a1 = fmaf((m1).x, readlanef(src, (kb) + 4), a1);  a1 = fmaf((m1).y, readlanef(src, (kb) + 5), a1); \
  a1 = fmaf((m1).z, readlanef(src, (kb) + 6), a1);  a1 = fmaf((m1).w, readlanef(src, (kb) + 7), a1); \
  a2 = fmaf((m2).x, readlanef(src, (kb) + 8), a2);  a2 = fmaf((m2).y, readlanef(src, (kb) + 9), a2); \
  a2 = fmaf((m2).z, readlanef(src, (kb) +10), a2);  a2 = fmaf((m2).w, readlanef(src, (kb) +11), a2); \
  a3 = fmaf((m3).x, readlanef(src, (kb) +12), a3);  a3 = fmaf((m3).y, readlanef(src, (kb) +13), a3); \
  a3 = fmaf((m3).z, readlanef(src, (kb) +14), a3);  a3 = fmaf((m3).w, readlanef(src, (kb) +15), a3);

// ---------- main kernel: r11 structure + mask-fma prefix + pipelined MLP loads ----------
// wave w handles shift-pair t = 64w + l (shifts t and t+128), full j range [0,128)
// window value for (t, j) = y[(255 - t + j) % 128] = yd[(255 - t) + j], yd[384] duplicated
__global__ __launch_bounds__(128, 4)
void mainK(const float* __restrict__ x, const float* __restrict__ y,
           const float* __restrict__ M4, const float* __restrict__ biasT,
           unsigned long long* __restrict__ partials, int* __restrict__ ticket,
           float* __restrict__ out){
  __shared__ float yd[384];     // yd[128+k] = yd[256+k] = y_res[k]
  __shared__ float sVal[2];
  __shared__ int   sIdx[2];
  __shared__ float sL[2], sC[2];
  __shared__ int   sOld;

  const int u = threadIdx.x;               // 0..127 ; u = 64w + l = owned element / output
  const int l = u & 63;
  const int w = u >> 6;
  const long base = (long)blockIdx.x * 128;

  float xlo = x[base + l], xhi = x[base + 64 + l];
  float ylo = y[base + l], yhi = y[base + 64 + l];
  const float yOwn0 = w ? yhi : ylo;
  const bool mOwn = (yOwn0 == IGNORE_OUT);
  float cnt = mOwn ? 0.f : 1.f;
  float lossAcc = 0.f;

  yd[128 + u] = yOwn0; yd[256 + u] = yOwn0;
  __syncthreads();

  for (int i = 0; i < NITER; ++i){
    const float4* Mp = (const float4*)(M4 + (size_t)i * 16384);
    // ---- issue MLP groups 0,1 + bias early: L2 latency hidden under scans+corr,
    //      drained at B1's implicit vmcnt(0) ----
    float4 A0, A1, A2, A3, B0, B1, B2, B3, C0, C1, C2, C3;
    MLD(A0, A1, A2, A3, 0)
    MLD(B0, B1, B2, B3, 1)
    float bias_i = biasT[i * 128 + u];

    // ---- window-norm prefix at t = 64w+l (DPP scan + DPP sums; zero DS) ----
    float own2 = w ? xhi * xhi : xlo * xlo;
    float oth2 = w ? xlo * xlo : xhi * xhi;
    float v = waveScanInc(own2);
    float osum  = waveSum(oth2);
    float total = readlanef(v, 63) + osum;
    float pref_t = w ? (v + osum) : v;     // inclusive prefix of x^2 at index t
    float ny2 = waveSum(ylo * ylo + yhi * yhi);

    // ---- corr: 128 b32 LDS window steps (2 lanes/bank = free), readlane broadcasts.
    //      Serial snap chain replaced by 4-way-split full sums + 4-way-split MASKED
    //      prefix ((l>=j)?w:0 cndmask) — all chains independent, ~64cy latency
    //      instead of ~400cy. ----
    const float* wp = yd + (255 - u);      // base in [128, 255]
    float s0=0.f,s1=0.f,s2=0.f,s3=0.f;     // first half  (j=0..63)  full sum
    float t0=0.f,t1=0.f,t2=0.f,t3=0.f;     // second half (j=64..127) full sum
    float p0=0.f,p1=0.f,p2=0.f,p3=0.f;     // masked prefix over own half
    if (w == 0){                           // t = l: prefix lives in first half
      #pragma unroll
      for (int j = 0; j < 64; j += 4){
        float wv0 = wp[j], wv1 = wp[j+1], wv2 = wp[j+2], wv3 = wp[j+3];
        float x0 = readlanef(xlo, j),   x1 = readlanef(xlo, j+1);
        float x2 = readlanef(xlo, j+2), x3 = readlanef(xlo, j+3);
        s0 = fmaf(wv0, x0, s0); s1 = fmaf(wv1, x1, s1);
        s2 = fmaf(wv2, x2, s2); s3 = fmaf(wv3, x3, s3);
        p0 = fmaf((l >= j    ) ? wv0 : 0.f, x0, p0);
        p1 = fmaf((l >= j + 1) ? wv1 : 0.f, x1, p1);
        p2 = fmaf((l >= j + 2) ? wv2 : 0.f, x2, p2);
        p3 = fmaf((l >= j + 3) ? wv3 : 0.f, x3, p3);
      }
      #pragma unroll
      for (int j = 0; j < 64; j += 4){
        float wv0 = wp[64+j], wv1 = wp[64+j+1], wv2 = wp[64+j+2], wv3 = wp[64+j+3];
        t0 = fmaf(wv0, readlanef(xhi, j),   t0);
        t1 = fmaf(wv1, readlanef(xhi, j+1), t1);
        t2 = fmaf(wv2, readlanef(xhi, j+2), t2);
        t3 = fmaf(wv3, readlanef(xhi, j+3), t3);
      }
    } else {                               // t = 64+l: first half all j<=t; prefix in second
      #pragma unroll
      for (int j = 0; j < 64; j += 4){
        float wv0 = wp[j], wv1 = wp[j+1], wv2 = wp[j+2], wv3 = wp[j+3];
        s0 = fmaf(wv0, readlanef(xlo, j),   s0);
        s1 = fmaf(wv1, readlanef(xlo, j+1), s1);
        s2 = fmaf(wv2, readlanef(xlo, j+2), s2);
        s3 = fmaf(wv3, readlanef(xlo, j+3), s3);
      }
      #pragma unroll
      for (int j = 0; j < 64; j += 4){
        float wv0 = wp[64+j], wv1 = wp[64+j+1], wv2 = wp[64+j+2], wv3 = wp[64+j+3];
        float x0 = readlanef(xhi, j),   x1 = readlanef(xhi, j+1);
        float x2 = readlanef(xhi, j+2), x3 = readlanef(xhi, j+3);
        t0 = fmaf(wv0, x0, t0); t1 = fmaf(wv1, x1, t1);
        t2 = fmaf(wv2, x2, t2); t3 = fmaf(wv3, x3, t3);
        p0 = fmaf((l >= j    ) ? wv0 : 0.f, x0, p0);
        p1 = fmaf((l >= j + 1) ? wv1 : 0.f, x1, p1);
        p2 = fmaf((l >= j + 2) ? wv2 : 0.f, x2, p2);
        p3 = fmaf((l >= j + 3) ? wv3 : 0.f, x3, p3);
      }
    }
    float Sh0 = (s0 + s1) + (s2 + s3);
    float Sh1 = (t0 + t1) + (t2 + t3);
    float P   = (p0 + p1) + (p2 + p3);
    float nt = Sh0 + Sh1;
    float n1 = w ? (Sh0 + P) : P;

    // ---- cosine sims via v_rsq; DPP argmax; cross-wave combine ----
    {
      bool yz = (ny2 == 0.f);
      float rNY = __builtin_amdgcn_rsqf(ny2);       // 1/||y||
      float nx2b = fmaxf(total - pref_t, 0.f);
      float s1v = (yz || pref_t == 0.f) ? 0.f : n1 * __builtin_amdgcn_rsqf(pref_t) * rNY;
      float s2v = (yz || nx2b  == 0.f) ? 0.f : (nt - n1) * __builtin_amdgcn_rsqf(nx2b) * rNY;
      if (u == 127) s2v = -INFINITY;       // shift 255 doesn't exist
      float bv = s1v; int bi = u;
      if (s2v > bv){ bv = s2v; bi = u + 128; }
      waveArgmax(bv, bi);
      if (l == 0){ sVal[w] = bv; sIdx[w] = bi; }
    }
    __syncthreads();                       // B1

    // ---- issue MLP group 2: hidden under argmax-combine + softmax/gathers ----
    MLD(C0, C1, C2, C3, 2)

    int sstar;
    {
      float v0 = sVal[0], v1 = sVal[1];
      int   i0 = sIdx[0], i1 = sIdx[1];
      sstar = (v1 > v0 || (v1 == v0 && i1 < i0)) ? i1 : i0;
    }

    // ---- x_aug + detached softmax (hw exp2/rcp; paired gathers) ----
    float xa, xb;
    gatherPair(xlo, xhi, sstar + l - 127, xa, xb);
    float ea = __builtin_amdgcn_exp2f(xa * ylo * LOG2E);
    float eb = __builtin_amdgcn_exp2f(xb * yhi * LOG2E);
    float rse = __builtin_amdgcn_rcpf(waveSum(ea + eb));
    float wlo = xa * (ea * rse), whi = xb * (eb * rse);   // xatt

    // ---- x_res update (reverse shift, paired gather) ----
    {
      float ga, gb;
      gatherPair(wlo, whi, l + 127 - sstar, ga, gb);
      xlo -= ga; xhi -= gb;
    }

    // ---- MLP: thread u -> output o = u; 3 rotating named-reg groups, 1-group-ahead
    //      prefetch; accumulation order identical to r11 baseline ----
    float ye;
    {
      float a0 = 0.f, a1 = 0.f, a2 = 0.f, a3 = 0.f;
      MFM(A0, A1, A2, A3, wlo, 0)   MLD(A0, A1, A2, A3, 3)
      MFM(B0, B1, B2, B3, wlo, 16)  MLD(B0, B1, B2, B3, 4)
      MFM(C0, C1, C2, C3, wlo, 32)  MLD(C0, C1, C2, C3, 5)
      MFM(A0, A1, A2, A3, wlo, 48)  MLD(A0, A1, A2, A3, 6)
      MFM(B0, B1, B2, B3, whi, 0)   MLD(B0, B1, B2, B3, 7)
      MFM(C0, C1, C2, C3, whi, 16)
      MFM(A0, A1, A2, A3, whi, 32)
      MFM(B0, B1, B2, B3, whi, 48)
      ye = ((a0 + a1) + (a2 + a3)) + bias_i;
    }

    // ---- loss on owned element + publish new y_res ----
    {
      float yOwn = w ? yhi : ylo;
      float df = ye - yOwn;
      if (!mOwn) lossAcc = fmaf(df, df, lossAcc);
      float yNew = yOwn - ye;
      yd[128 + u] = yNew; yd[256 + u] = yNew;
    }
    __syncthreads();                       // B2
    ylo = yd[128 + l];                     // refresh register copies from yd
    yhi = yd[192 + l];
  }

  // ---- block loss/cnt, partial store + ticket; last block finalizes ----
  lossAcc = waveSum(lossAcc);
  cnt     = waveSum(cnt);
  if (l == 0){ sL[w] = lossAcc; sC[w] = cnt; }
  __syncthreads();
  if (u == 0){
    union { float2 f; unsigned long long v; } pk;
    pk.f.x = sL[0] + sL[1];
    pk.f.y = sC[0] + sC[1];
    __hip_atomic_store(&partials[blockIdx.x], pk.v, __ATOMIC_RELEASE, __HIP_MEMORY_SCOPE_AGENT);
    sOld = __hip_atomic_fetch_add(ticket, 1, __ATOMIC_ACQ_REL, __HIP_MEMORY_SCOPE_AGENT);
  }
  __syncthreads();
  if (sOld == NBLK - 1){
    float ls = 0.f, cs = 0.f;
    for (int g = u; g < NBLK; g += 128){
      union { float2 f; unsigned long long v; } pk;
      pk.v = __hip_atomic_load(&partials[g], __ATOMIC_ACQUIRE, __HIP_MEMORY_SCOPE_AGENT);
      ls += pk.f.x; cs += pk.f.y;
    }
    ls = waveSum(ls); cs = waveSum(cs);
    if (l == 0){ sL[w] = ls; sC[w] = cs; }
    __syncthreads();
    if (u == 0) out[0] = (sL[0] + sL[1]) / ((float)NITER * (sC[0] + sC[1]));
  }
}

extern "C" void kernel_launch(void* const* d_in, const int* in_sizes, int n_in,
                              void* d_out, int out_size, void* d_ws, size_t ws_size,
                              hipStream_t stream){
  const float* x  = (const float*)d_in[0];
  const float* y  = (const float*)d_in[1];
  const float* w1 = (const float*)d_in[2];
  const float* b1 = (const float*)d_in[3];
  const float* w2 = (const float*)d_in[4];
  const float* b2 = (const float*)d_in[5];
  float* out = (float*)d_out;

  // ws: [0,4) ticket ; [256, 256+256K) M4 ; +2K biasT ; +16K partials
  int*   ticket = (int*)d_ws;
  float* M4     = (float*)((char*)d_ws + 256);
  float* biasT  = (float*)((char*)d_ws + 256 + 4 * 128 * 128 * sizeof(float));
  unsigned long long* partials =
      (unsigned long long*)((char*)d_ws + 256 + 4 * 128 * 128 * sizeof(float) + 4 * 128 * sizeof(float));

  prepK<<<517, 256, 0, stream>>>(w1, b1, w2, b2, M4, biasT, ticket);
  mainK<<<NBLK, 128, 0, stream>>>(x, y, M4, biasT, partials, ticket, out);
}

// Round 3
// 155.668 us; speedup vs baseline: 1.4692x; 1.1360x over previous
//
#include <hip/hip_runtime.h>
#include <math.h>

// B=4, T=512, IDIM=128, HDIM=1024, CDIM=256
#define NBLK  2048            // one row per block, 2 waves per block
#define NITER 4
#define IGNORE_OUT 10000.0f
#define LOG2E 1.44269504088896340736f

__device__ __forceinline__ float readlanef(float v, int lane){
  return __int_as_float(__builtin_amdgcn_readlane(__float_as_int(v), lane));
}

// ---- DPP wave primitives (gfx9 ladder: row_shr 1/2/4/8, bcast15->rows1,3, bcast31->rows2,3) ----
__device__ __forceinline__ float waveScanInc(float v){
  v += __int_as_float(__builtin_amdgcn_update_dpp(0, __float_as_int(v), 0x111, 0xF, 0xF, true));
  v += __int_as_float(__builtin_amdgcn_update_dpp(0, __float_as_int(v), 0x112, 0xF, 0xF, true));
  v += __int_as_float(__builtin_amdgcn_update_dpp(0, __float_as_int(v), 0x114, 0xF, 0xF, true));
  v += __int_as_float(__builtin_amdgcn_update_dpp(0, __float_as_int(v), 0x118, 0xF, 0xF, true));
  v += __int_as_float(__builtin_amdgcn_update_dpp(0, __float_as_int(v), 0x142, 0xA, 0xF, true));
  v += __int_as_float(__builtin_amdgcn_update_dpp(0, __float_as_int(v), 0x143, 0xC, 0xF, true));
  return v;                                // lane l = sum of lanes 0..l
}
__device__ __forceinline__ float waveSum(float v){
  return readlanef(waveScanInc(v), 63);
}
__device__ __forceinline__ void waveArgmax(float &v, int &i){
#define AMSTEP(ctrl, rm) { \
    float ov = __int_as_float(__builtin_amdgcn_update_dpp(__float_as_int(v), __float_as_int(v), ctrl, rm, 0xF, false)); \
    int   oi = __builtin_amdgcn_update_dpp(i, i, ctrl, rm, 0xF, false); \
    bool take = (ov > v) || (ov == v && oi < i); \
    v = take ? ov : v; i = take ? oi : i; }
  AMSTEP(0x111, 0xF) AMSTEP(0x112, 0xF) AMSTEP(0x114, 0xF)
  AMSTEP(0x118, 0xF) AMSTEP(0x142, 0xA) AMSTEP(0x143, 0xC)
#undef AMSTEP
  v = readlanef(v, 63);
  i = __builtin_amdgcn_readlane(i, 63);
}
// paired gather: a = vec[idx], b = vec[idx+64] (0 outside [0,128)); 2 bpermutes total
__device__ __forceinline__ void gatherPair(float v0, float v1, int idx, float &a, float &b){
  int c = idx & 63;
  float g0 = __shfl(v0, c, 64);
  float g1 = __shfl(v1, c, 64);
  a = ((unsigned)idx < 128u) ? ((idx & 64) ? g1 : g0) : 0.f;
  int idx2 = idx + 64;
  b = ((unsigned)idx2 < 128u) ? ((idx2 & 64) ? g1 : g0) : 0.f;
}

// ---------- prep kernel: M4[i] = w2[:, i*256:(i+1)*256] @ w1[i*256:(i+1)*256, :] ----------
// 256 threads: h = tid>>7 splits the 256-deep K range in half, LDS combine.
__global__ __launch_bounds__(256)
void prepK(const float* __restrict__ w1, const float* __restrict__ b1,
           const float* __restrict__ w2, const float* __restrict__ b2,
           float* __restrict__ M4, float* __restrict__ biasT, int* __restrict__ ticket){
  const int blk = blockIdx.x;
  const int tid = threadIdx.x;
  const int u = tid & 127, h = tid >> 7;
  __shared__ float part[256];
  if (blk < 512){
    int i = blk >> 7, o = blk & 127;
    const float* w1p = w1 + (i * 256 + h * 128) * 128 + u;   // coalesced over d=u
    const float* w2p = w2 + o * 1024 + i * 256 + h * 128;    // thread-uniform
    float a0 = 0.f, a1 = 0.f, a2 = 0.f, a3 = 0.f;
    #pragma unroll 8
    for (int c = 0; c < 128; c += 4){
      a0 = fmaf(w1p[(c + 0) * 128], w2p[c + 0], a0);
      a1 = fmaf(w1p[(c + 1) * 128], w2p[c + 1], a1);
      a2 = fmaf(w1p[(c + 2) * 128], w2p[c + 2], a2);
      a3 = fmaf(w1p[(c + 3) * 128], w2p[c + 3], a3);
    }
    part[tid] = (a0 + a1) + (a2 + a3);
    __syncthreads();
    if (h == 0) M4[i * 16384 + (u >> 2) * 512 + o * 4 + (u & 3)] = part[u] + part[128 + u];
  } else if (blk < 516){
    int i = blk - 512;
    const float* w2p = w2 + u * 1024 + i * 256 + h * 128;
    const float* b1p = b1 + i * 256 + h * 128;
    float a0 = h ? 0.f : b2[u], a1 = 0.f, a2 = 0.f, a3 = 0.f;
    #pragma unroll 8
    for (int c = 0; c < 128; c += 4){
      a0 = fmaf(b1p[c + 0], w2p[c + 0], a0);
      a1 = fmaf(b1p[c + 1], w2p[c + 1], a1);
      a2 = fmaf(b1p[c + 2], w2p[c + 2], a2);
      a3 = fmaf(b1p[c + 3], w2p[c + 3], a3);
    }
    part[tid] = (a0 + a1) + (a2 + a3);
    __syncthreads();
    if (h == 0) biasT[i * 128 + u] = part[u] + part[128 + u];
  } else {
    if (tid == 0) *ticket = 0;
  }
}

// M-group load/consume macros — NAMED float4 scalars only (no arrays: spill-proof).
// Group gg covers M float4-rows 4gg..4gg+3 = k-values 16gg..16gg+15.
#define MLD(d0, d1, d2, d3, gg) \
  d0 = Mp[((gg) * 4 + 0) * 128 + u]; d1 = Mp[((gg) * 4 + 1) * 128 + u]; \
  d2 = Mp[((gg) * 4 + 2) * 128 + u]; d3 = Mp[((gg) * 4 + 3) * 128 + u];
#define MFM(m0, m1, m2, m3, src, kb) \
  a0 = fmaf((m0).x, readlanef(src, (kb) + 0), a0);  a0 = fmaf((m0).y, readlanef(src, (kb) + 1), a0); \
  a0 = fmaf((m0).z, readlanef(src, (kb) + 2), a0);  a0 = fmaf((m0).w, readlanef(src, (kb) + 3), a0); \
  a1 = fmaf((m1).x, readlanef(src, (kb) + 4), a1);  a1 = fmaf((m1).y, readlanef(src, (kb) + 5), a1); \
  a1 = fmaf((m1).z, readlanef(src, (kb) + 6), a1);  a1 = fmaf((m1).w, readlanef(src, (kb) + 7), a1); \
  a2 = fmaf((m2).x, readlanef(src, (kb) + 8), a2);  a2 = fmaf((m2).y, readlanef(src, (kb) + 9), a2); \
  a2 = fmaf((m2).z, readlanef(src, (kb) +10), a2);  a2 = fmaf((m2).w, readlanef(src, (kb) +11), a2); \
  a3 = fmaf((m3).x, readlanef(src, (kb) +12), a3);  a3 = fmaf((m3).y, readlanef(src, (kb) +13), a3); \
  a3 = fmaf((m3).z, readlanef(src, (kb) +14), a3);  a3 = fmaf((m3).w, readlanef(src, (kb) +15), a3);

// ---------- main kernel: r11 structure + mask-fma prefix + local 2-buffer MLP pipeline ----------
// wave w handles shift-pair t = 64w + l (shifts t and t+128), full j range [0,128)
// window value for (t, j) = y[(255 - t + j) % 128] = yd[(255 - t) + j], yd[384] duplicated
__global__ __launch_bounds__(128, 4)
void mainK(const float* __restrict__ x, const float* __restrict__ y,
           const float* __restrict__ M4, const float* __restrict__ biasT,
           unsigned long long* __restrict__ partials, int* __restrict__ ticket,
           float* __restrict__ out){
  __shared__ float yd[384];     // yd[128+k] = yd[256+k] = y_res[k]
  __shared__ float sVal[2];
  __shared__ int   sIdx[2];
  __shared__ float sL[2], sC[2];
  __shared__ int   sOld;

  const int u = threadIdx.x;               // 0..127 ; u = 64w + l = owned element / output
  const int l = u & 63;
  const int w = u >> 6;
  const long base = (long)blockIdx.x * 128;

  float xlo = x[base + l], xhi = x[base + 64 + l];
  float ylo = y[base + l], yhi = y[base + 64 + l];
  const float yOwn0 = w ? yhi : ylo;
  const bool mOwn = (yOwn0 == IGNORE_OUT);
  float cnt = mOwn ? 0.f : 1.f;
  float lossAcc = 0.f;

  yd[128 + u] = yOwn0; yd[256 + u] = yOwn0;
  __syncthreads();

  for (int i = 0; i < NITER; ++i){
    const float4* Mp = (const float4*)(M4 + (size_t)i * 16384);

    // ---- window-norm prefix at t = 64w+l (DPP scan + DPP sums; zero DS) ----
    float own2 = w ? xhi * xhi : xlo * xlo;
    float oth2 = w ? xlo * xlo : xhi * xhi;
    float v = waveScanInc(own2);
    float osum  = waveSum(oth2);
    float total = readlanef(v, 63) + osum;
    float pref_t = w ? (v + osum) : v;     // inclusive prefix of x^2 at index t
    float ny2 = waveSum(ylo * ylo + yhi * yhi);

    // ---- corr: 128 b32 LDS window steps (2 lanes/bank = free), readlane broadcasts.
    //      Serial snap chain replaced by 4-way-split full sums + 4-way-split MASKED
    //      prefix ((l>=j)?w:0 cndmask) — all chains independent (~64cy vs ~450cy). ----
    const float* wp = yd + (255 - u);      // base in [128, 255]
    float s0=0.f,s1=0.f,s2=0.f,s3=0.f;     // first half  (j=0..63)  full sum
    float t0=0.f,t1=0.f,t2=0.f,t3=0.f;     // second half (j=64..127) full sum
    float p0=0.f,p1=0.f,p2=0.f,p3=0.f;     // masked prefix over own half
    if (w == 0){                           // t = l: prefix lives in first half
      #pragma unroll
      for (int j = 0; j < 64; j += 4){
        float wv0 = wp[j], wv1 = wp[j+1], wv2 = wp[j+2], wv3 = wp[j+3];
        float x0 = readlanef(xlo, j),   x1 = readlanef(xlo, j+1);
        float x2 = readlanef(xlo, j+2), x3 = readlanef(xlo, j+3);
        s0 = fmaf(wv0, x0, s0); s1 = fmaf(wv1, x1, s1);
        s2 = fmaf(wv2, x2, s2); s3 = fmaf(wv3, x3, s3);
        p0 = fmaf((l >= j    ) ? wv0 : 0.f, x0, p0);
        p1 = fmaf((l >= j + 1) ? wv1 : 0.f, x1, p1);
        p2 = fmaf((l >= j + 2) ? wv2 : 0.f, x2, p2);
        p3 = fmaf((l >= j + 3) ? wv3 : 0.f, x3, p3);
      }
      #pragma unroll
      for (int j = 0; j < 64; j += 4){
        float wv0 = wp[64+j], wv1 = wp[64+j+1], wv2 = wp[64+j+2], wv3 = wp[64+j+3];
        t0 = fmaf(wv0, readlanef(xhi, j),   t0);
        t1 = fmaf(wv1, readlanef(xhi, j+1), t1);
        t2 = fmaf(wv2, readlanef(xhi, j+2), t2);
        t3 = fmaf(wv3, readlanef(xhi, j+3), t3);
      }
    } else {                               // t = 64+l: first half all j<=t; prefix in second
      #pragma unroll
      for (int j = 0; j < 64; j += 4){
        float wv0 = wp[j], wv1 = wp[j+1], wv2 = wp[j+2], wv3 = wp[j+3];
        s0 = fmaf(wv0, readlanef(xlo, j),   s0);
        s1 = fmaf(wv1, readlanef(xlo, j+1), s1);
        s2 = fmaf(wv2, readlanef(xlo, j+2), s2);
        s3 = fmaf(wv3, readlanef(xlo, j+3), s3);
      }
      #pragma unroll
      for (int j = 0; j < 64; j += 4){
        float wv0 = wp[64+j], wv1 = wp[64+j+1], wv2 = wp[64+j+2], wv3 = wp[64+j+3];
        float x0 = readlanef(xhi, j),   x1 = readlanef(xhi, j+1);
        float x2 = readlanef(xhi, j+2), x3 = readlanef(xhi, j+3);
        t0 = fmaf(wv0, x0, t0); t1 = fmaf(wv1, x1, t1);
        t2 = fmaf(wv2, x2, t2); t3 = fmaf(wv3, x3, t3);
        p0 = fmaf((l >= j    ) ? wv0 : 0.f, x0, p0);
        p1 = fmaf((l >= j + 1) ? wv1 : 0.f, x1, p1);
        p2 = fmaf((l >= j + 2) ? wv2 : 0.f, x2, p2);
        p3 = fmaf((l >= j + 3) ? wv3 : 0.f, x3, p3);
      }
    }
    float Sh0 = (s0 + s1) + (s2 + s3);
    float Sh1 = (t0 + t1) + (t2 + t3);
    float P   = (p0 + p1) + (p2 + p3);
    float nt = Sh0 + Sh1;
    float n1 = w ? (Sh0 + P) : P;

    // ---- cosine sims via v_rsq; DPP argmax; cross-wave combine ----
    {
      bool yz = (ny2 == 0.f);
      float rNY = __builtin_amdgcn_rsqf(ny2);       // 1/||y||
      float nx2b = fmaxf(total - pref_t, 0.f);
      float s1v = (yz || pref_t == 0.f) ? 0.f : n1 * __builtin_amdgcn_rsqf(pref_t) * rNY;
      float s2v = (yz || nx2b  == 0.f) ? 0.f : (nt - n1) * __builtin_amdgcn_rsqf(nx2b) * rNY;
      if (u == 127) s2v = -INFINITY;       // shift 255 doesn't exist
      float bv = s1v; int bi = u;
      if (s2v > bv){ bv = s2v; bi = u + 128; }
      waveArgmax(bv, bi);
      if (l == 0){ sVal[w] = bv; sIdx[w] = bi; }
    }
    __syncthreads();                       // B1

    // ---- issue MLP groups 0,1 + bias: L2 latency hidden under argmax-combine +
    //      softmax + gathers; live ranges start HERE (never across corr/barriers) ----
    float4 A0, A1, A2, A3, B0, B1, B2, B3;
    MLD(A0, A1, A2, A3, 0)
    MLD(B0, B1, B2, B3, 1)
    float bias_i = biasT[i * 128 + u];

    int sstar;
    {
      float v0 = sVal[0], v1 = sVal[1];
      int   i0 = sIdx[0], i1 = sIdx[1];
      sstar = (v1 > v0 || (v1 == v0 && i1 < i0)) ? i1 : i0;
    }

    // ---- x_aug + detached softmax (hw exp2/rcp; paired gathers) ----
    float xa, xb;
    gatherPair(xlo, xhi, sstar + l - 127, xa, xb);
    float ea = __builtin_amdgcn_exp2f(xa * ylo * LOG2E);
    float eb = __builtin_amdgcn_exp2f(xb * yhi * LOG2E);
    float rse = __builtin_amdgcn_rcpf(waveSum(ea + eb));
    float wlo = xa * (ea * rse), whi = xb * (eb * rse);   // xatt

    // ---- x_res update (reverse shift, paired gather) ----
    {
      float ga, gb;
      gatherPair(wlo, whi, l + 127 - sstar, ga, gb);
      xlo -= ga; xhi -= gb;
    }

    // ---- MLP: thread u -> output o = u; 2 rotating named-reg buffers (32 VGPRs),
    //      one-group-ahead prefetch; accumulation order identical to r11 baseline ----
    float ye;
    {
      float a0 = 0.f, a1 = 0.f, a2 = 0.f, a3 = 0.f;
      MFM(A0, A1, A2, A3, wlo, 0)   MLD(A0, A1, A2, A3, 2)
      MFM(B0, B1, B2, B3, wlo, 16)  MLD(B0, B1, B2, B3, 3)
      MFM(A0, A1, A2, A3, wlo, 32)  MLD(A0, A1, A2, A3, 4)
      MFM(B0, B1, B2, B3, wlo, 48)  MLD(B0, B1, B2, B3, 5)
      MFM(A0, A1, A2, A3, whi, 0)   MLD(A0, A1, A2, A3, 6)
      MFM(B0, B1, B2, B3, whi, 16)  MLD(B0, B1, B2, B3, 7)
      MFM(A0, A1, A2, A3, whi, 32)
      MFM(B0, B1, B2, B3, whi, 48)
      ye = ((a0 + a1) + (a2 + a3)) + bias_i;
    }

    // ---- loss on owned element + publish new y_res ----
    {
      float yOwn = w ? yhi : ylo;
      float df = ye - yOwn;
      if (!mOwn) lossAcc = fmaf(df, df, lossAcc);
      float yNew = yOwn - ye;
      yd[128 + u] = yNew; yd[256 + u] = yNew;
    }
    __syncthreads();                       // B2
    ylo = yd[128 + l];                     // refresh register copies from yd
    yhi = yd[192 + l];
  }

  // ---- block loss/cnt, partial store + ticket; last block finalizes ----
  lossAcc = waveSum(lossAcc);
  cnt     = waveSum(cnt);
  if (l == 0){ sL[w] = lossAcc; sC[w] = cnt; }
  __syncthreads();
  if (u == 0){
    union { float2 f; unsigned long long v; } pk;
    pk.f.x = sL[0] + sL[1];
    pk.f.y = sC[0] + sC[1];
    __hip_atomic_store(&partials[blockIdx.x], pk.v, __ATOMIC_RELEASE, __HIP_MEMORY_SCOPE_AGENT);
    sOld = __hip_atomic_fetch_add(ticket, 1, __ATOMIC_ACQ_REL, __HIP_MEMORY_SCOPE_AGENT);
  }
  __syncthreads();
  if (sOld == NBLK - 1){
    float ls = 0.f, cs = 0.f;
    for (int g = u; g < NBLK; g += 128){
      union { float2 f; unsigned long long v; } pk;
      pk.v = __hip_atomic_load(&partials[g], __ATOMIC_ACQUIRE, __HIP_MEMORY_SCOPE_AGENT);
      ls += pk.f.x; cs += pk.f.y;
    }
    ls = waveSum(ls); cs = waveSum(cs);
    if (l == 0){ sL[w] = ls; sC[w] = cs; }
    __syncthreads();
    if (u == 0) out[0] = (sL[0] + sL[1]) / ((float)NITER * (sC[0] + sC[1]));
  }
}

extern "C" void kernel_launch(void* const* d_in, const int* in_sizes, int n_in,
                              void* d_out, int out_size, void* d_ws, size_t ws_size,
                              hipStream_t stream){
  const float* x  = (const float*)d_in[0];
  const float* y  = (const float*)d_in[1];
  const float* w1 = (const float*)d_in[2];
  const float* b1 = (const float*)d_in[3];
  const float* w2 = (const float*)d_in[4];
  const float* b2 = (const float*)d_in[5];
  float* out = (float*)d_out;

  // ws: [0,4) ticket ; [256, 256+256K) M4 ; +2K biasT ; +16K partials
  int*   ticket = (int*)d_ws;
  float* M4     = (float*)((char*)d_ws + 256);
  float* biasT  = (float*)((char*)d_ws + 256 + 4 * 128 * 128 * sizeof(float));
  unsigned long long* partials =
      (unsigned long long*)((char*)d_ws + 256 + 4 * 128 * 128 * sizeof(float) + 4 * 128 * sizeof(float));

  prepK<<<517, 256, 0, stream>>>(w1, b1, w2, b2, M4, biasT, ticket);
  mainK<<<NBLK, 128, 0, stream>>>(x, y, M4, biasT, partials, ticket, out);
}